// Round 4
// baseline (745.361 us; speedup 1.0000x reference)
//
#include <hip/hip_runtime.h>
#include <hip/hip_bf16.h>
#include <cstdint>
#include <cstddef>

#define ALPHA 0.2f
#define MLP_SLOPE 0.01f

typedef short bf16x8 __attribute__((ext_vector_type(8)));
typedef float f32x4 __attribute__((ext_vector_type(4)));
typedef unsigned short ushort_t;

__device__ __forceinline__ float lrelu(float x, float s) { return x > 0.f ? x : x * s; }
__device__ __forceinline__ ushort_t f2bf(float x) {
  __hip_bfloat16 h = __float2bfloat16(x);
  return *reinterpret_cast<ushort_t*>(&h);
}
__device__ __forceinline__ float bf2f(ushort_t u) {
  union { unsigned int i; float f; } v; v.i = ((unsigned int)u) << 16; return v.f;
}

// ---------------------------------------------------------------------------
// split fp32 -> (hi, lo) bf16, elementwise (4 elems/thread)
// ---------------------------------------------------------------------------
__global__ __launch_bounds__(256) void split_f(
    const float* __restrict__ in, ushort_t* __restrict__ hi,
    ushort_t* __restrict__ lo)
{
  int idx = blockIdx.x * 256 + threadIdx.x;
  float4 v = ((const float4*)in)[idx];
  ushort4 h, l;
  h.x = f2bf(v.x); l.x = f2bf(v.x - bf2f(h.x));
  h.y = f2bf(v.y); l.y = f2bf(v.y - bf2f(h.y));
  h.z = f2bf(v.z); l.z = f2bf(v.z - bf2f(h.z));
  h.w = f2bf(v.w); l.w = f2bf(v.w - bf2f(h.w));
  ((ushort4*)hi)[idx] = h;
  ((ushort4*)lo)[idx] = l;
}

// ---------------------------------------------------------------------------
// transpose + split: W[K,N] -> T[N,K] hi/lo bf16 (batch via blockIdx.y)
// ---------------------------------------------------------------------------
__global__ __launch_bounds__(256) void split_t(
    const float* __restrict__ W, ushort_t* __restrict__ Thi,
    ushort_t* __restrict__ Tlo, int K, int N)
{
  int idx = blockIdx.x * 256 + threadIdx.x;
  if (idx >= K * N) return;
  int k = idx / N, n = idx - k * N;
  size_t b = (size_t)blockIdx.y * K * N;
  float v = W[b + idx];
  ushort_t h = f2bf(v);
  size_t o = b + (size_t)n * K + k;
  Thi[o] = h; Tlo[o] = f2bf(v - bf2f(h));
}

// ---------------------------------------------------------------------------
// Split-precision bf16 MFMA GEMM: C = act(A[M,K] @ Bt[N,K]^T + bias)
// Block tile 128(M)x64(N), 4 waves of 64x32, k-step 32, LDS pad 42 (2-way max).
// 3-pass hi/lo accumulation. Batch via blockIdx.z.
// ---------------------------------------------------------------------------
__global__ __launch_bounds__(256, 2) void gemm_bf16s(
    const ushort_t* __restrict__ Ahi, const ushort_t* __restrict__ Alo,
    const ushort_t* __restrict__ Bthi, const ushort_t* __restrict__ Btlo,
    const float* __restrict__ bias, float* __restrict__ Cf,
    ushort_t* __restrict__ Chi, ushort_t* __restrict__ Clo,
    int M, int N, int K, float slope, int act)
{
  __shared__ ushort_t Ah[128][42], Al[128][42], Bh[64][42], Bl[64][42];
  const size_t boff = (size_t)blockIdx.z * N * K;
  const size_t coff = (size_t)blockIdx.z * M * N;
  const int t = threadIdx.x;
  const int m0 = blockIdx.y * 128, n0 = blockIdx.x * 64;
  const int wave = t >> 6;
  const int wm = (wave & 1) * 64, wn = (wave >> 1) * 32;
  const int l16 = t & 15, quad = (t >> 4) & 3;
  const int tr = t & 127;
  f32x4 acc[4][2];
#pragma unroll
  for (int i = 0; i < 4; ++i)
#pragma unroll
    for (int j = 0; j < 2; ++j) acc[i][j] = (f32x4){0.f, 0.f, 0.f, 0.f};

  for (int k0 = 0; k0 < K; k0 += 32) {
    __syncthreads();
    {
      const size_t abase = (size_t)(m0 + tr) * K + k0;
      if (t < 128) {
#pragma unroll
        for (int j = 0; j < 4; ++j)
          *(uint4*)&Ah[tr][j * 8] = *(const uint4*)&Ahi[abase + j * 8];
      } else {
#pragma unroll
        for (int j = 0; j < 4; ++j)
          *(uint4*)&Al[tr][j * 8] = *(const uint4*)&Alo[abase + j * 8];
        const int br = tr & 63;
        const size_t bbase = boff + (size_t)(n0 + br) * K + k0;
        if (tr < 64) {
#pragma unroll
          for (int j = 0; j < 4; ++j)
            *(uint4*)&Bh[br][j * 8] = *(const uint4*)&Bthi[bbase + j * 8];
        } else {
#pragma unroll
          for (int j = 0; j < 4; ++j)
            *(uint4*)&Bl[br][j * 8] = *(const uint4*)&Btlo[bbase + j * 8];
        }
      }
    }
    __syncthreads();
    bf16x8 afh[4], afl[4], bfh[2], bfl[2];
#pragma unroll
    for (int mt = 0; mt < 4; ++mt) {
      afh[mt] = *(const bf16x8*)&Ah[wm + mt * 16 + l16][quad * 8];
      afl[mt] = *(const bf16x8*)&Al[wm + mt * 16 + l16][quad * 8];
    }
#pragma unroll
    for (int nt = 0; nt < 2; ++nt) {
      bfh[nt] = *(const bf16x8*)&Bh[wn + nt * 16 + l16][quad * 8];
      bfl[nt] = *(const bf16x8*)&Bl[wn + nt * 16 + l16][quad * 8];
    }
#pragma unroll
    for (int mt = 0; mt < 4; ++mt)
#pragma unroll
      for (int nt = 0; nt < 2; ++nt) {
        acc[mt][nt] = __builtin_amdgcn_mfma_f32_16x16x32_bf16(afh[mt], bfh[nt], acc[mt][nt], 0, 0, 0);
        acc[mt][nt] = __builtin_amdgcn_mfma_f32_16x16x32_bf16(afh[mt], bfl[nt], acc[mt][nt], 0, 0, 0);
        acc[mt][nt] = __builtin_amdgcn_mfma_f32_16x16x32_bf16(afl[mt], bfh[nt], acc[mt][nt], 0, 0, 0);
      }
  }
#pragma unroll
  for (int mt = 0; mt < 4; ++mt)
#pragma unroll
    for (int nt = 0; nt < 2; ++nt)
#pragma unroll
      for (int rg = 0; rg < 4; ++rg) {
        int m = m0 + wm + mt * 16 + quad * 4 + rg;
        int n = n0 + wn + nt * 16 + l16;
        float v = acc[mt][nt][rg];
        if (bias) v += bias[n];
        if (act) v = lrelu(v, slope);
        size_t o = coff + (size_t)m * N + n;
        if (Cf) Cf[o] = v;
        if (Chi) {
          ushort_t h = f2bf(v);
          Chi[o] = h; Clo[o] = f2bf(v - bf2f(h));
        }
      }
}

// ---------------------------------------------------------------------------
// s1/s2: per-row dots of h with a1/a2 (one wave per row, both heads)
// ---------------------------------------------------------------------------
__global__ __launch_bounds__(256) void s_kernel(
    const float* __restrict__ hbuf, const float* __restrict__ a1,
    const float* __restrict__ a2, float* __restrict__ s1, float* __restrict__ s2)
{
  const int gw = (blockIdx.x * 256 + threadIdx.x) >> 6;
  const int lane = threadIdx.x & 63;
#pragma unroll
  for (int hh = 0; hh < 2; ++hh) {
    float4 hv = ((const float4*)(hbuf + ((size_t)hh * 8192 + gw) * 256))[lane];
    float4 a1v = ((const float4*)(a1 + hh * 256))[lane];
    float4 a2v = ((const float4*)(a2 + hh * 256))[lane];
    float p1 = hv.x * a1v.x + hv.y * a1v.y + hv.z * a1v.z + hv.w * a1v.w;
    float p2 = hv.x * a2v.x + hv.y * a2v.y + hv.z * a2v.z + hv.w * a2v.w;
    for (int off = 32; off > 0; off >>= 1) {
      p1 += __shfl_xor(p1, off);
      p2 += __shfl_xor(p2, off);
    }
    if (lane == 0) {
      s1[hh * 8192 + gw] = p1;
      s2[hh * 8192 + gw] = p2;
    }
  }
}

// ---------------------------------------------------------------------------
// Pack h (fp32 [head][j][c]) into MFMA B-fragment order:
// Bpack[(((head*256 + kblk)*16 + ntile)*64 + lane)*8 + e]
//   = bf16(h[head][kblk*32 + (lane>>4)*8 + e][ntile*16 + (lane&15)])
// ---------------------------------------------------------------------------
__global__ __launch_bounds__(256) void h_pack(
    const float* __restrict__ hbuf, ushort_t* __restrict__ Bpack)
{
  int gid = blockIdx.x * 256 + threadIdx.x;   // 0 .. 524287
  int lane = gid & 63;
  int ntile = (gid >> 6) & 15;
  int kblk = (gid >> 10) & 255;
  int head = gid >> 18;
  int c = ntile * 16 + (lane & 15);
  int jb = kblk * 32 + (lane >> 4) * 8;
  ushort_t o[8];
#pragma unroll
  for (int e = 0; e < 8; ++e)
    o[e] = f2bf(hbuf[((size_t)head * 8192 + jb + e) * 256 + c]);
  *(uint4*)&Bpack[(size_t)gid * 8] = *(uint4*)o;
}

// ---------------------------------------------------------------------------
// MFMA attention v3: BARRIER-FREE. Wave = (head, n-half); each lane generates
// its own A-fragment W elements in-register (in-lane adj int4 loads + s2
// broadcasts + preloaded s1); B-frags direct from L2-resident Bpack; adj/s2
// prefetched one k-step ahead. No LDS, no __syncthreads in the K-loop.
// Block: 64 rows x 256 cols x 2 heads; grid (128 rowblocks, 4 k-slices).
// ---------------------------------------------------------------------------
__global__ __launch_bounds__(256, 2) void attn_mfma3(
    const ushort_t* __restrict__ Bpack, const float* __restrict__ s1g,
    const float* __restrict__ s2g, const int* __restrict__ adj,
    ushort_t* __restrict__ pacc, float* __restrict__ pl)
{
  const int t = threadIdx.x;
  const int i0 = blockIdx.x * 64;
  const int js = blockIdx.y;
  const int kbase = js * 2048;
  const int wave = t >> 6, head = wave >> 1, nh = wave & 1;
  const int l16 = t & 15, oct = (t >> 4) & 3;
  const int l63 = t & 63;

  // preload s1 for this lane's 4 rows
  float s1v[4];
#pragma unroll
  for (int mt = 0; mt < 4; ++mt)
    s1v[mt] = s1g[(size_t)head * 8192 + i0 + mt * 16 + l16];
  const float* s2h = s2g + (size_t)head * 8192;

  f32x4 acc[4][8];
#pragma unroll
  for (int m = 0; m < 4; ++m)
#pragma unroll
    for (int n = 0; n < 8; ++n) acc[m][n] = (f32x4){0.f, 0.f, 0.f, 0.f};
  float rs[4] = {0.f, 0.f, 0.f, 0.f};

  // adj row pointers for this lane's 4 rows
  const int* arow[4];
#pragma unroll
  for (int mt = 0; mt < 4; ++mt)
    arow[mt] = adj + (size_t)(i0 + mt * 16 + l16) * 8192;

  // prefetch step 0: adj (4 rows x 8 k) + s2 (8 k)
  int4 pa0[4], pa1[4];
  float4 ps2a, ps2b;
  {
    const int kk = kbase + oct * 8;
#pragma unroll
    for (int mt = 0; mt < 4; ++mt) {
      pa0[mt] = *(const int4*)&arow[mt][kk];
      pa1[mt] = *(const int4*)&arow[mt][kk + 4];
    }
    ps2a = *(const float4*)&s2h[kk];
    ps2b = *(const float4*)&s2h[kk + 4];
  }

  for (int kt = 0; kt < 64; ++kt) {
    // ---- issue B-fragment loads (L2) early; latency hidden by W-gen ----
    const int kblk = js * 64 + kt;
    const ushort_t* bb =
        Bpack + ((((size_t)head * 256 + kblk) * 16 + nh * 8) * 64 + l63) * 8;
    bf16x8 Bf[8];
#pragma unroll
    for (int nt = 0; nt < 8; ++nt)
      Bf[nt] = *(const bf16x8*)&bb[nt * 512];

    // ---- generate A-fragments (W) in-register from prefetched adj/s2 ----
    float s2v[8] = {ps2a.x, ps2a.y, ps2a.z, ps2a.w,
                    ps2b.x, ps2b.y, ps2b.z, ps2b.w};
    bf16x8 Af[4];
#pragma unroll
    for (int mt = 0; mt < 4; ++mt) {
      int av[8] = {pa0[mt].x, pa0[mt].y, pa0[mt].z, pa0[mt].w,
                   pa1[mt].x, pa1[mt].y, pa1[mt].z, pa1[mt].w};
      ushort_t w[8] __attribute__((aligned(16)));
      float r = 0.f;
#pragma unroll
      for (int e = 0; e < 8; ++e) {
        float ev = s1v[mt] + s2v[e];
        ev = fmaxf(ev, 0.f) + ALPHA * fminf(ev, 0.f);
        float wv = av[e] > 0 ? __expf(ev) : 0.f;
        r += wv;
        w[e] = f2bf(wv);
      }
      rs[mt] += r;
      Af[mt] = *(const bf16x8*)w;
    }

    // ---- prefetch next step's adj/s2 (HBM latency hidden by MFMAs) ----
    if (kt < 63) {
      const int kk = kbase + (kt + 1) * 32 + oct * 8;
#pragma unroll
      for (int mt = 0; mt < 4; ++mt) {
        pa0[mt] = *(const int4*)&arow[mt][kk];
        pa1[mt] = *(const int4*)&arow[mt][kk + 4];
      }
      ps2a = *(const float4*)&s2h[kk];
      ps2b = *(const float4*)&s2h[kk + 4];
    }

    // ---- MFMA ----
#pragma unroll
    for (int mt = 0; mt < 4; ++mt)
#pragma unroll
      for (int nt = 0; nt < 8; ++nt)
        acc[mt][nt] = __builtin_amdgcn_mfma_f32_16x16x32_bf16(
            Af[mt], Bf[nt], acc[mt][nt], 0, 0, 0);
  }

  // ---- denominators: reduce over the 4 octs holding each row ----
#pragma unroll
  for (int mt = 0; mt < 4; ++mt) {
    rs[mt] += __shfl_xor(rs[mt], 16);
    rs[mt] += __shfl_xor(rs[mt], 32);
  }
  if (nh == 0 && oct == 0) {
#pragma unroll
    for (int mt = 0; mt < 4; ++mt)
      pl[((size_t)js * 2 + head) * 8192 + i0 + mt * 16 + l16] = rs[mt];
  }

  // ---- store bf16 partial numerators (layout verified in R3) ----
  const int n0 = nh * 128;
#pragma unroll
  for (int mt = 0; mt < 4; ++mt)
#pragma unroll
    for (int nt = 0; nt < 8; ++nt)
#pragma unroll
      for (int rg = 0; rg < 4; ++rg) {
        int row = i0 + mt * 16 + oct * 4 + rg;
        int col = n0 + nt * 16 + l16;
        pacc[(((size_t)js * 2 + head) * 8192 + row) * 256 + col] =
            f2bf(acc[mt][nt][rg]);
      }
}

// ---------------------------------------------------------------------------
// Finalize (+ fused llm copy): sum 4 j-parts, /l, leaky_relu, l2-normalize,
// +bias, head-mean -> embed[:, 512:768]; embed[:, 0:512] = llm_emb.
// ---------------------------------------------------------------------------
__global__ __launch_bounds__(256) void attn_finalize(
    const ushort_t* __restrict__ pacc, const float* __restrict__ pl,
    const float* __restrict__ bg, const float* __restrict__ llm,
    float* __restrict__ embed)
{
  __shared__ float red[256];
  const int r = blockIdx.x;
  const int t = threadIdx.x;
  if (t < 128)
    *(float4*)&embed[(size_t)r * 768 + t * 4] =
        *(const float4*)&llm[(size_t)r * 512 + t * 4];
  float o[2], nrm[2];
#pragma unroll
  for (int hh = 0; hh < 2; ++hh) {
    float num = 0.f, l = 0.f;
#pragma unroll
    for (int js = 0; js < 4; ++js) {
      num += bf2f(pacc[(((size_t)js * 2 + hh) * 8192 + r) * 256 + t]);
      l += pl[((size_t)js * 2 + hh) * 8192 + r];
    }
    o[hh] = lrelu(num / l, ALPHA);
  }
  for (int hh = 0; hh < 2; ++hh) {
    __syncthreads();
    red[t] = o[hh] * o[hh];
    __syncthreads();
    for (int s = 128; s > 0; s >>= 1) {
      if (t < s) red[t] += red[t + s];
      __syncthreads();
    }
    nrm[hh] = fmaxf(sqrtf(red[0]), 1e-12f);
  }
  embed[(size_t)r * 768 + 512 + t] =
      0.5f * (o[0] / nrm[0] + bg[t] + o[1] / nrm[1] + bg[256 + t]);
}

// ---------------------------------------------------------------------------
__global__ __launch_bounds__(256) void pred_kernel(
    const float* __restrict__ z2, const int* __restrict__ ts,
    float* __restrict__ out, int E)
{
  const int gw = (blockIdx.x * 256 + threadIdx.x) >> 6;
  const int lane = threadIdx.x & 63;
  if (gw >= E) return;
  const int a = ts[gw * 2], b = ts[gw * 2 + 1];
  float4 va = ((const float4*)(z2 + (size_t)a * 256))[lane];
  float4 vb = ((const float4*)(z2 + (size_t)b * 256))[lane];
  float p = va.x * vb.x + va.y * vb.y + va.z * vb.z + va.w * vb.w;
  for (int off = 32; off > 0; off >>= 1) p += __shfl_xor(p, off);
  if (lane == 0) out[gw] = p;
}

// ---------------------------------------------------------------------------
extern "C" void kernel_launch(void* const* d_in, const int* in_sizes, int n_in,
                              void* d_out, int out_size, void* d_ws, size_t ws_size,
                              hipStream_t stream) {
  const float* x   = (const float*)d_in[0];
  const int*   adj = (const int*)d_in[1];
  const int*   ts  = (const int*)d_in[2];
  const float* llm = (const float*)d_in[3];
  const float* Wg  = (const float*)d_in[4];
  const float* a1  = (const float*)d_in[5];
  const float* a2  = (const float*)d_in[6];
  const float* bg  = (const float*)d_in[7];
  const float* W1  = (const float*)d_in[8];
  const float* b1  = (const float*)d_in[9];
  const float* W2  = (const float*)d_in[10];
  const float* b2  = (const float*)d_in[11];
  float* out = (float*)d_out;
  float* ws  = (float*)d_ws;
  const int E = in_sizes[2] / 2;

  // ---- workspace layout (float words), with lifetime overlays ----
  float*    hbuf  = ws;                             // [0, 4194304)
  ushort_t* Bpack = (ushort_t*)(ws + 4194304);      // [4194304, 6291456)
  float*    embed = ws;                             // overlay hbuf+Bpack
  ushort_t* xhi   = (ushort_t*)(ws + 6291456);
  ushort_t* xlo   = (ushort_t*)(ws + 8388608);
  ushort_t* z1hi  = xhi;                            // overlay
  ushort_t* z1lo  = xlo;
  float*    s1    = ws + 10485760;
  float*    s2    = ws + 10502144;
  float*    pl    = ws + 10518528;
  ushort_t* pacc  = (ushort_t*)(ws + 10584064);
  ushort_t* ehi   = (ushort_t*)(ws + 10584064);     // overlay pacc
  ushort_t* elo   = (ushort_t*)(ws + 13729792);
  float*    z2    = ws + 16875520;
  ushort_t* wgthi = (ushort_t*)(ws + 18972672);
  ushort_t* wgtlo = (ushort_t*)(ws + 19103744);
  ushort_t* w1thi = (ushort_t*)(ws + 19234816);
  ushort_t* w1tlo = (ushort_t*)(ws + 19431424);
  ushort_t* w2thi = (ushort_t*)(ws + 19628032);
  ushort_t* w2tlo = (ushort_t*)(ws + 19693568);

  // 1. splits / transposes
  split_f<<<4096, 256, 0, stream>>>(x, xhi, xlo);
  split_t<<<dim3(512, 2), 256, 0, stream>>>(Wg, wgthi, wgtlo, 512, 256);
  split_t<<<dim3(1536, 1), 256, 0, stream>>>(W1, w1thi, w1tlo, 768, 512);
  split_t<<<dim3(512, 1), 256, 0, stream>>>(W2, w2thi, w2tlo, 512, 256);
  // 2. h[head] = x @ Wg[head]  (split bf16, fp32 out)
  gemm_bf16s<<<dim3(4, 64, 2), 256, 0, stream>>>(
      xhi, xlo, wgthi, wgtlo, nullptr, hbuf, nullptr, nullptr,
      8192, 256, 512, 0.f, 0);
  // 3. s1/s2 row dots
  s_kernel<<<2048, 256, 0, stream>>>(hbuf, a1, a2, s1, s2);
  // 4. pack h into B-fragment order
  h_pack<<<2048, 256, 0, stream>>>(hbuf, Bpack);
  // 5. MFMA attention partials (barrier-free)
  attn_mfma3<<<dim3(128, 4), 256, 0, stream>>>(Bpack, s1, s2, adj, pacc, pl);
  // 6. embed = [llm | attn epilogue]
  attn_finalize<<<8192, 256, 0, stream>>>(pacc, pl, bg, llm, embed);
  // 7. split embed (pacc dead now)
  split_f<<<6144, 256, 0, stream>>>(embed, ehi, elo);
  // 8. z1 = LR(embed @ W1 + b1) -> hi/lo bf16 directly
  gemm_bf16s<<<dim3(8, 64, 1), 256, 0, stream>>>(
      ehi, elo, w1thi, w1tlo, b1, nullptr, z1hi, z1lo,
      8192, 512, 768, MLP_SLOPE, 1);
  // 9. z2 = LR(z1 @ W2 + b2) fp32
  gemm_bf16s<<<dim3(4, 64, 1), 256, 0, stream>>>(
      z1hi, z1lo, w2thi, w2tlo, b2, z2, nullptr, nullptr,
      8192, 256, 512, MLP_SLOPE, 1);
  // 10. edge dots
  pred_kernel<<<(E * 64 + 255) / 256, 256, 0, stream>>>(z2, ts, out, E);
}

// Round 5
// 663.339 us; speedup vs baseline: 1.1237x; 1.1237x over previous
//
#include <hip/hip_runtime.h>
#include <hip/hip_bf16.h>
#include <cstdint>
#include <cstddef>

#define ALPHA 0.2f
#define MLP_SLOPE 0.01f

typedef short bf16x8 __attribute__((ext_vector_type(8)));
typedef float f32x4 __attribute__((ext_vector_type(4)));
typedef unsigned short ushort_t;

// raw barrier: syncs LDS exchange WITHOUT draining vmcnt (global prefetches
// stay in flight across it) — the __syncthreads() vmcnt(0) drain was the
// R3 stall; the wave-dup adj traffic was the R4 regression.
#define ASM_BARRIER() __asm__ __volatile__("s_waitcnt lgkmcnt(0)\n\ts_barrier" ::: "memory")

__device__ __forceinline__ float lrelu(float x, float s) { return x > 0.f ? x : x * s; }
__device__ __forceinline__ ushort_t f2bf(float x) {
  __hip_bfloat16 h = __float2bfloat16(x);
  return *reinterpret_cast<ushort_t*>(&h);
}
__device__ __forceinline__ float bf2f(ushort_t u) {
  union { unsigned int i; float f; } v; v.i = ((unsigned int)u) << 16; return v.f;
}

// ---------------------------------------------------------------------------
// split fp32 -> (hi, lo) bf16, elementwise (4 elems/thread)
// ---------------------------------------------------------------------------
__global__ __launch_bounds__(256) void split_f(
    const float* __restrict__ in, ushort_t* __restrict__ hi,
    ushort_t* __restrict__ lo)
{
  int idx = blockIdx.x * 256 + threadIdx.x;
  float4 v = ((const float4*)in)[idx];
  ushort4 h, l;
  h.x = f2bf(v.x); l.x = f2bf(v.x - bf2f(h.x));
  h.y = f2bf(v.y); l.y = f2bf(v.y - bf2f(h.y));
  h.z = f2bf(v.z); l.z = f2bf(v.z - bf2f(h.z));
  h.w = f2bf(v.w); l.w = f2bf(v.w - bf2f(h.w));
  ((ushort4*)hi)[idx] = h;
  ((ushort4*)lo)[idx] = l;
}

// ---------------------------------------------------------------------------
// Pack weights W[K,N] (batch via blockIdx.y) into MFMA B-fragment order:
// out[((nblk*(K/32) + kblk)*64 + lane)*8 + e]
//   = W[(kblk*32 + (lane>>4)*8 + e)*N + nblk*16 + (lane&15)]   (hi/lo split)
// ---------------------------------------------------------------------------
__global__ __launch_bounds__(256) void pack_wt(
    const float* __restrict__ W, ushort_t* __restrict__ hi,
    ushort_t* __restrict__ lo, int K, int N)
{
  int gid = blockIdx.x * 256 + threadIdx.x;   // [0, N*K/8)
  int lane = gid & 63;
  int kbc = K >> 5;
  int kblk = (gid >> 6) % kbc;
  int nblk = (gid >> 6) / kbc;
  size_t b = (size_t)blockIdx.y * K * N;
  int col = nblk * 16 + (lane & 15);
  int krow = kblk * 32 + (lane >> 4) * 8;
  ushort_t h[8] __attribute__((aligned(16)));
  ushort_t l[8] __attribute__((aligned(16)));
#pragma unroll
  for (int e = 0; e < 8; ++e) {
    float v = W[b + (size_t)(krow + e) * N + col];
    h[e] = f2bf(v);
    l[e] = f2bf(v - bf2f(h[e]));
  }
  *(uint4*)&hi[b + (size_t)gid * 8] = *(uint4*)h;
  *(uint4*)&lo[b + (size_t)gid * 8] = *(uint4*)l;
}

// ---------------------------------------------------------------------------
// LDS-free split-bf16 MFMA GEMM: C = act(A[M,K] @ W + bias).
// A (hi/lo) read as fragments directly from global (cacheline-exact pattern);
// W pre-packed in B-frag order (hi/lo, L2-resident). 3-pass hi/lo accum.
// Block 256 thr = 4 waves, block tile 128M x 64N, wave tile 64M x 32N.
// No LDS, no barriers; 1-deep register pipeline. Batch via blockIdx.z (B,C).
// ---------------------------------------------------------------------------
__global__ __launch_bounds__(256) void gemm_nolds(
    const ushort_t* __restrict__ Ahi, const ushort_t* __restrict__ Alo,
    const ushort_t* __restrict__ Bph, const ushort_t* __restrict__ Bpl,
    const float* __restrict__ bias, float* __restrict__ Cf,
    ushort_t* __restrict__ Chi, ushort_t* __restrict__ Clo,
    int M, int N, int K, float slope, int act)
{
  const size_t boff = (size_t)blockIdx.z * N * K;
  const size_t coff = (size_t)blockIdx.z * M * N;
  const int t = threadIdx.x;
  const int wave = t >> 6, l63 = t & 63;
  const int l16 = t & 15, oct = (t >> 4) & 3, quad = oct;
  const int wm = (wave & 1) * 64, wn = (wave >> 1) * 32;
  const int m0 = blockIdx.y * 128 + wm;
  const int nb = blockIdx.x * 4 + (wave >> 1) * 2;
  const int nbase = blockIdx.x * 64 + wn;
  const int ksteps = K >> 5;

  const ushort_t* aph[4];
  const ushort_t* apl[4];
#pragma unroll
  for (int mt = 0; mt < 4; ++mt) {
    size_t o = (size_t)(m0 + mt * 16 + l16) * K + oct * 8;
    aph[mt] = Ahi + o;
    apl[mt] = Alo + o;
  }
  const ushort_t* bph[2];
  const ushort_t* bpl[2];
#pragma unroll
  for (int nt = 0; nt < 2; ++nt) {
    size_t o = boff + ((size_t)(nb + nt) * ksteps * 64 + l63) * 8;
    bph[nt] = Bph + o;
    bpl[nt] = Bpl + o;
  }

  f32x4 acc[4][2];
#pragma unroll
  for (int i = 0; i < 4; ++i)
#pragma unroll
    for (int j = 0; j < 2; ++j) acc[i][j] = (f32x4){0.f, 0.f, 0.f, 0.f};

#define LOADF(AH, AL, BH, BL, KB)                                         \
  {                                                                       \
    _Pragma("unroll") for (int mt = 0; mt < 4; ++mt) {                    \
      AH[mt] = *(const bf16x8*)(aph[mt] + (size_t)(KB) * 32);             \
      AL[mt] = *(const bf16x8*)(apl[mt] + (size_t)(KB) * 32);             \
    }                                                                     \
    _Pragma("unroll") for (int nt = 0; nt < 2; ++nt) {                    \
      BH[nt] = *(const bf16x8*)(bph[nt] + (size_t)(KB) * 512);            \
      BL[nt] = *(const bf16x8*)(bpl[nt] + (size_t)(KB) * 512);            \
    }                                                                     \
  }
#define MF(AH, AL, BH, BL)                                                \
  {                                                                       \
    _Pragma("unroll") for (int mt = 0; mt < 4; ++mt)                      \
    _Pragma("unroll") for (int nt = 0; nt < 2; ++nt) {                    \
      acc[mt][nt] = __builtin_amdgcn_mfma_f32_16x16x32_bf16(AH[mt], BH[nt], acc[mt][nt], 0, 0, 0); \
      acc[mt][nt] = __builtin_amdgcn_mfma_f32_16x16x32_bf16(AH[mt], BL[nt], acc[mt][nt], 0, 0, 0); \
      acc[mt][nt] = __builtin_amdgcn_mfma_f32_16x16x32_bf16(AL[mt], BH[nt], acc[mt][nt], 0, 0, 0); \
    }                                                                     \
  }

  bf16x8 ah0[4], al0[4], bh0[2], bl0[2];
  bf16x8 ah1[4], al1[4], bh1[2], bl1[2];
  LOADF(ah0, al0, bh0, bl0, 0)
  for (int kb = 0; kb < ksteps; kb += 2) {
    LOADF(ah1, al1, bh1, bl1, kb + 1)
    MF(ah0, al0, bh0, bl0)
    if (kb + 2 < ksteps) LOADF(ah0, al0, bh0, bl0, kb + 2)
    MF(ah1, al1, bh1, bl1)
  }
#undef LOADF
#undef MF

#pragma unroll
  for (int mt = 0; mt < 4; ++mt)
#pragma unroll
    for (int nt = 0; nt < 2; ++nt)
#pragma unroll
      for (int rg = 0; rg < 4; ++rg) {
        int m = m0 + mt * 16 + quad * 4 + rg;
        int n = nbase + nt * 16 + l16;
        float v = acc[mt][nt][rg];
        if (bias) v += bias[n];
        if (act) v = lrelu(v, slope);
        size_t o = coff + (size_t)m * N + n;
        if (Cf) Cf[o] = v;
        if (Chi) {
          ushort_t h = f2bf(v);
          Chi[o] = h; Clo[o] = f2bf(v - bf2f(h));
        }
      }
}

// ---------------------------------------------------------------------------
// s1/s2: per-row dots of h with a1/a2 (one wave per row, both heads)
// ---------------------------------------------------------------------------
__global__ __launch_bounds__(256) void s_kernel(
    const float* __restrict__ hbuf, const float* __restrict__ a1,
    const float* __restrict__ a2, float* __restrict__ s1, float* __restrict__ s2)
{
  const int gw = (blockIdx.x * 256 + threadIdx.x) >> 6;
  const int lane = threadIdx.x & 63;
#pragma unroll
  for (int hh = 0; hh < 2; ++hh) {
    float4 hv = ((const float4*)(hbuf + ((size_t)hh * 8192 + gw) * 256))[lane];
    float4 a1v = ((const float4*)(a1 + hh * 256))[lane];
    float4 a2v = ((const float4*)(a2 + hh * 256))[lane];
    float p1 = hv.x * a1v.x + hv.y * a1v.y + hv.z * a1v.z + hv.w * a1v.w;
    float p2 = hv.x * a2v.x + hv.y * a2v.y + hv.z * a2v.z + hv.w * a2v.w;
    for (int off = 32; off > 0; off >>= 1) {
      p1 += __shfl_xor(p1, off);
      p2 += __shfl_xor(p2, off);
    }
    if (lane == 0) {
      s1[hh * 8192 + gw] = p1;
      s2[hh * 8192 + gw] = p2;
    }
  }
}

// ---------------------------------------------------------------------------
// Pack h (fp32 [head][j][c]) into MFMA B-fragment order (bf16)
// ---------------------------------------------------------------------------
__global__ __launch_bounds__(256) void h_pack(
    const float* __restrict__ hbuf, ushort_t* __restrict__ Bpack)
{
  int gid = blockIdx.x * 256 + threadIdx.x;   // 0 .. 524287
  int lane = gid & 63;
  int ntile = (gid >> 6) & 15;
  int kblk = (gid >> 10) & 255;
  int head = gid >> 18;
  int c = ntile * 16 + (lane & 15);
  int jb = kblk * 32 + (lane >> 4) * 8;
  ushort_t o[8] __attribute__((aligned(16)));
#pragma unroll
  for (int e = 0; e < 8; ++e)
    o[e] = f2bf(hbuf[((size_t)head * 8192 + jb + e) * 256 + c]);
  *(uint4*)&Bpack[(size_t)gid * 8] = *(uint4*)o;
}

// ---------------------------------------------------------------------------
// MFMA attention v4: R3 structure (adj read ONCE per block by generator
// threads, W exchanged via double-buffered LDS in A-frag order, B-frags
// direct from L2-resident Bpack) + raw s_barrier (no vmcnt drain) + B loads
// issued before W-gen so L2 latency hides under exp VALU.
// Block: 64 rows x 256 cols x 2 heads, 4 waves = (head, n-half).
// Grid (128 rowblocks, 4 k-slices of 2048).
// ---------------------------------------------------------------------------
__global__ __launch_bounds__(256, 2) void attn_mfma4(
    const ushort_t* __restrict__ Bpack, const float* __restrict__ s1g,
    const float* __restrict__ s2g, const int* __restrict__ adj,
    ushort_t* __restrict__ pacc, float* __restrict__ pl)
{
  __shared__ ushort_t Wlds[2][2][4][64][8];   // [buf][head][mt][lane][8]
  const int t = threadIdx.x;
  const int i0 = blockIdx.x * 64;
  const int js = blockIdx.y;
  const int kbase = js * 2048;
  // generator mapping: row wr (0..63), k-octet kq (0..3)
  const int wr = t >> 2, kq = t & 3;
  const int glane = kq * 16 + (wr & 15);
  const int gmt = wr >> 4;
  const float s1v0 = s1g[i0 + wr];
  const float s1v1 = s1g[8192 + i0 + wr];
  // consumer mapping
  const int wave = t >> 6, head = wave >> 1, nh = wave & 1;
  const int l16 = t & 15, quad = (t >> 4) & 3;
  const int l63 = t & 63;
  f32x4 acc[4][8];
#pragma unroll
  for (int m = 0; m < 4; ++m)
#pragma unroll
    for (int n = 0; n < 8; ++n) acc[m][n] = (f32x4){0.f, 0.f, 0.f, 0.f};
  float rs0 = 0.f, rs1 = 0.f;

  const int* arow = adj + (size_t)(i0 + wr) * 8192;
  // prefetch step 0
  int4 pa0, pa1;
  float4 p20a, p20b, p21a, p21b;
  {
    const int kk = kbase + kq * 8;
    pa0 = *(const int4*)&arow[kk];
    pa1 = *(const int4*)&arow[kk + 4];
    p20a = *(const float4*)&s2g[kk];
    p20b = *(const float4*)&s2g[kk + 4];
    p21a = *(const float4*)&s2g[8192 + kk];
    p21b = *(const float4*)&s2g[8192 + kk + 4];
  }
  for (int kt = 0; kt < 64; ++kt) {
    const int buf = kt & 1;
    // ---- issue B-fragment loads FIRST (L2 latency hides under W-gen) ----
    const int kblk = js * 64 + kt;
    const ushort_t* bb =
        Bpack + ((((size_t)head * 256 + kblk) * 16 + nh * 8) * 64 + l63) * 8;
    bf16x8 Bf[8];
#pragma unroll
    for (int nt = 0; nt < 8; ++nt)
      Bf[nt] = *(const bf16x8*)&bb[nt * 512];

    // ---- generate W for this step from prefetched regs ----
    {
      int am[8] = {pa0.x, pa0.y, pa0.z, pa0.w, pa1.x, pa1.y, pa1.z, pa1.w};
      float s20[8] = {p20a.x, p20a.y, p20a.z, p20a.w, p20b.x, p20b.y, p20b.z, p20b.w};
      float s21[8] = {p21a.x, p21a.y, p21a.z, p21a.w, p21b.x, p21b.y, p21b.z, p21b.w};
      ushort_t w0[8] __attribute__((aligned(16)));
      ushort_t w1[8] __attribute__((aligned(16)));
#pragma unroll
      for (int e = 0; e < 8; ++e) {
        float e0 = s1v0 + s20[e];
        float e1 = s1v1 + s21[e];
        e0 = fmaxf(e0, 0.f) + ALPHA * fminf(e0, 0.f);
        e1 = fmaxf(e1, 0.f) + ALPHA * fminf(e1, 0.f);
        float v0 = am[e] > 0 ? __expf(e0) : 0.f;
        float v1 = am[e] > 0 ? __expf(e1) : 0.f;
        rs0 += v0; rs1 += v1;
        w0[e] = f2bf(v0); w1[e] = f2bf(v1);
      }
      *(uint4*)&Wlds[buf][0][gmt][glane][0] = *(uint4*)w0;
      *(uint4*)&Wlds[buf][1][gmt][glane][0] = *(uint4*)w1;
    }
    // ---- prefetch next step's adj/s2 (stays in flight across barrier) ----
    if (kt < 63) {
      const int kk = kbase + (kt + 1) * 32 + kq * 8;
      pa0 = *(const int4*)&arow[kk];
      pa1 = *(const int4*)&arow[kk + 4];
      p20a = *(const float4*)&s2g[kk];
      p20b = *(const float4*)&s2g[kk + 4];
      p21a = *(const float4*)&s2g[8192 + kk];
      p21b = *(const float4*)&s2g[8192 + kk + 4];
    }
    // ---- raw barrier: waits LDS ops only, vmcnt untouched ----
    ASM_BARRIER();
    // ---- fragments + MFMA ----
    bf16x8 Af[4];
#pragma unroll
    for (int mt = 0; mt < 4; ++mt)
      Af[mt] = *(const bf16x8*)&Wlds[buf][head][mt][l63][0];
#pragma unroll
    for (int mt = 0; mt < 4; ++mt)
#pragma unroll
      for (int nt = 0; nt < 8; ++nt)
        acc[mt][nt] = __builtin_amdgcn_mfma_f32_16x16x32_bf16(
            Af[mt], Bf[nt], acc[mt][nt], 0, 0, 0);
  }
  // ---- denominators: reduce over the 4 kq-threads of each row ----
  rs0 += __shfl_xor(rs0, 1); rs0 += __shfl_xor(rs0, 2);
  rs1 += __shfl_xor(rs1, 1); rs1 += __shfl_xor(rs1, 2);
  if (kq == 0) {
    pl[((size_t)js * 2 + 0) * 8192 + i0 + wr] = rs0;
    pl[((size_t)js * 2 + 1) * 8192 + i0 + wr] = rs1;
  }
  // ---- store bf16 partial numerators ----
  const int n0 = nh * 128;
#pragma unroll
  for (int mt = 0; mt < 4; ++mt)
#pragma unroll
    for (int nt = 0; nt < 8; ++nt)
#pragma unroll
      for (int rg = 0; rg < 4; ++rg) {
        int row = i0 + mt * 16 + quad * 4 + rg;
        int col = n0 + nt * 16 + l16;
        pacc[(((size_t)js * 2 + head) * 8192 + row) * 256 + col] =
            f2bf(acc[mt][nt][rg]);
      }
}

// ---------------------------------------------------------------------------
// Finalize (+ fused llm copy): sum 4 j-parts, /l, leaky_relu, l2-normalize,
// +bias, head-mean -> embed[:, 512:768]; embed[:, 0:512] = llm_emb.
// ---------------------------------------------------------------------------
__global__ __launch_bounds__(256) void attn_finalize(
    const ushort_t* __restrict__ pacc, const float* __restrict__ pl,
    const float* __restrict__ bg, const float* __restrict__ llm,
    float* __restrict__ embed)
{
  __shared__ float red[256];
  const int r = blockIdx.x;
  const int t = threadIdx.x;
  if (t < 128)
    *(float4*)&embed[(size_t)r * 768 + t * 4] =
        *(const float4*)&llm[(size_t)r * 512 + t * 4];
  float o[2], nrm[2];
#pragma unroll
  for (int hh = 0; hh < 2; ++hh) {
    float num = 0.f, l = 0.f;
#pragma unroll
    for (int js = 0; js < 4; ++js) {
      num += bf2f(pacc[(((size_t)js * 2 + hh) * 8192 + r) * 256 + t]);
      l += pl[((size_t)js * 2 + hh) * 8192 + r];
    }
    o[hh] = lrelu(num / l, ALPHA);
  }
  for (int hh = 0; hh < 2; ++hh) {
    __syncthreads();
    red[t] = o[hh] * o[hh];
    __syncthreads();
    for (int s = 128; s > 0; s >>= 1) {
      if (t < s) red[t] += red[t + s];
      __syncthreads();
    }
    nrm[hh] = fmaxf(sqrtf(red[0]), 1e-12f);
  }
  embed[(size_t)r * 768 + 512 + t] =
      0.5f * (o[0] / nrm[0] + bg[t] + o[1] / nrm[1] + bg[256 + t]);
}

// ---------------------------------------------------------------------------
__global__ __launch_bounds__(256) void pred_kernel(
    const float* __restrict__ z2, const int* __restrict__ ts,
    float* __restrict__ out, int E)
{
  const int gw = (blockIdx.x * 256 + threadIdx.x) >> 6;
  const int lane = threadIdx.x & 63;
  if (gw >= E) return;
  const int a = ts[gw * 2], b = ts[gw * 2 + 1];
  float4 va = ((const float4*)(z2 + (size_t)a * 256))[lane];
  float4 vb = ((const float4*)(z2 + (size_t)b * 256))[lane];
  float p = va.x * vb.x + va.y * vb.y + va.z * vb.z + va.w * vb.w;
  for (int off = 32; off > 0; off >>= 1) p += __shfl_xor(p, off);
  if (lane == 0) out[gw] = p;
}

// ---------------------------------------------------------------------------
extern "C" void kernel_launch(void* const* d_in, const int* in_sizes, int n_in,
                              void* d_out, int out_size, void* d_ws, size_t ws_size,
                              hipStream_t stream) {
  const float* x   = (const float*)d_in[0];
  const int*   adj = (const int*)d_in[1];
  const int*   ts  = (const int*)d_in[2];
  const float* llm = (const float*)d_in[3];
  const float* Wg  = (const float*)d_in[4];
  const float* a1  = (const float*)d_in[5];
  const float* a2  = (const float*)d_in[6];
  const float* bg  = (const float*)d_in[7];
  const float* W1  = (const float*)d_in[8];
  const float* b1  = (const float*)d_in[9];
  const float* W2  = (const float*)d_in[10];
  const float* b2  = (const float*)d_in[11];
  float* out = (float*)d_out;
  float* ws  = (float*)d_ws;
  const int E = in_sizes[2] / 2;

  // ---- workspace layout (float words), with lifetime overlays ----
  float*    hbuf  = ws;                             // [0, 4194304)
  ushort_t* Bpack = (ushort_t*)(ws + 4194304);      // [4194304, 6291456)
  float*    embed = ws;                             // overlay hbuf+Bpack
  ushort_t* xhi   = (ushort_t*)(ws + 6291456);
  ushort_t* xlo   = (ushort_t*)(ws + 8388608);
  ushort_t* z1hi  = xhi;                            // overlay (x dead)
  ushort_t* z1lo  = xlo;
  float*    s1    = ws + 10485760;
  float*    s2    = ws + 10502144;
  float*    pl    = ws + 10518528;
  ushort_t* pacc  = (ushort_t*)(ws + 10584064);
  ushort_t* ehi   = (ushort_t*)(ws + 10584064);     // overlay pacc (dead)
  ushort_t* elo   = (ushort_t*)(ws + 13729792);
  float*    z2    = ws + 16875520;
  ushort_t* wgphi = (ushort_t*)(ws + 18972672);     // 2*256*512
  ushort_t* wgplo = (ushort_t*)(ws + 19103744);
  ushort_t* w1phi = (ushort_t*)(ws + 19234816);     // 512*768
  ushort_t* w1plo = (ushort_t*)(ws + 19431424);
  ushort_t* w2phi = (ushort_t*)(ws + 19628032);     // 256*512
  ushort_t* w2plo = (ushort_t*)(ws + 19693568);

  // 1. splits / weight packing
  split_f<<<4096, 256, 0, stream>>>(x, xhi, xlo);
  pack_wt<<<dim3(64, 2), 256, 0, stream>>>(Wg, wgphi, wgplo, 512, 256);
  pack_wt<<<dim3(192, 1), 256, 0, stream>>>(W1, w1phi, w1plo, 768, 512);
  pack_wt<<<dim3(64, 1), 256, 0, stream>>>(W2, w2phi, w2plo, 512, 256);
  // 2. h[head] = x @ Wg[head]  (LDS-free split GEMM, fp32 out)
  gemm_nolds<<<dim3(4, 64, 2), 256, 0, stream>>>(
      xhi, xlo, wgphi, wgplo, nullptr, hbuf, nullptr, nullptr,
      8192, 256, 512, 0.f, 0);
  // 3. s1/s2 row dots
  s_kernel<<<2048, 256, 0, stream>>>(hbuf, a1, a2, s1, s2);
  // 4. pack h into B-fragment order
  h_pack<<<2048, 256, 0, stream>>>(hbuf, Bpack);
  // 5. MFMA attention partials (raw-barrier pipeline)
  attn_mfma4<<<dim3(128, 4), 256, 0, stream>>>(Bpack, s1, s2, adj, pacc, pl);
  // 6. embed = [llm | attn epilogue]
  attn_finalize<<<8192, 256, 0, stream>>>(pacc, pl, bg, llm, embed);
  // 7. split embed (pacc dead now)
  split_f<<<6144, 256, 0, stream>>>(embed, ehi, elo);
  // 8. z1 = LR(embed @ W1 + b1) -> hi/lo bf16 directly
  gemm_nolds<<<dim3(8, 64, 1), 256, 0, stream>>>(
      ehi, elo, w1phi, w1plo, b1, nullptr, z1hi, z1lo,
      8192, 512, 768, MLP_SLOPE, 1);
  // 9. z2 = LR(z1 @ W2 + b2) fp32
  gemm_nolds<<<dim3(4, 64, 1), 256, 0, stream>>>(
      z1hi, z1lo, w2phi, w2plo, b2, z2, nullptr, nullptr,
      8192, 256, 512, MLP_SLOPE, 1);
  // 10. edge dots
  pred_kernel<<<(E * 64 + 255) / 256, 256, 0, stream>>>(z2, ts, out, E);
}